// Round 9
// baseline (938.849 us; speedup 1.0000x reference)
//
#include <hip/hip_runtime.h>
#include <stdint.h>

#define LDIM 1024
#define DDIM 256
#define FDIM 32
#define NSEG 64
#define BM 32

typedef __attribute__((ext_vector_type(4))) float f32x4;
typedef __attribute__((ext_vector_type(8))) short short8;
typedef __attribute__((ext_vector_type(4))) unsigned int u32x4;

__device__ __forceinline__ unsigned int pk2bf(float a, float b) {
  union { float f; unsigned int u; } x, y; x.f = a; y.f = b;
  unsigned int ua = x.u + 0x7FFFu + ((x.u >> 16) & 1u);
  unsigned int ub = y.u + 0x7FFFu + ((y.u >> 16) & 1u);
  return (ua >> 16) | (ub & 0xFFFF0000u);
}

__device__ __forceinline__ unsigned short f2bf(float f) {
  union { float f; unsigned int u; } v; v.f = f;
  unsigned int r = v.u + 0x7FFFu + ((v.u >> 16) & 1u);
  return (unsigned short)(r >> 16);
}

__device__ __forceinline__ short8 pack8(f32x4 a, f32x4 b) {
  union { u32x4 u; short8 s; } r;
  r.u[0] = pk2bf(a[0], a[1]); r.u[1] = pk2bf(a[2], a[3]);
  r.u[2] = pk2bf(b[0], b[1]); r.u[3] = pk2bf(b[2], b[3]);
  return r.s;
}

__device__ __forceinline__ float bflo(unsigned int u) {
  union { unsigned int u; float f; } v; v.u = u << 16; return v.f;
}
__device__ __forceinline__ float bfhi(unsigned int u) {
  union { unsigned int u; float f; } v; v.u = u & 0xFFFF0000u; return v.f;
}

// ---- prep: w1tz[f][k] = bf16((W1@Wa1)[k][f]), f=0..31 (z-GEMM B, 64 KB) ----
__global__ void prep_w1tz(const float* __restrict__ W1, const float* __restrict__ Wa1,
                          unsigned short* __restrict__ w1tz) {
  __shared__ float rowf[DDIM];
  const int k = blockIdx.x;
  const int t = threadIdx.x;
  rowf[t] = W1[(size_t)k * DDIM + t];
  __syncthreads();
  if (t < FDIM) {
    float a = 0.f;
    for (int c = 0; c < DDIM; ++c) a += rowf[c] * Wa1[c * FDIM + t];
    w1tz[(size_t)t * LDIM + k] = f2bf(a);
  }
}

// ---- prep: zero Xacc/accE, bz = b1@Wa1 + ba1 ----
__global__ void prep_misc(const float* __restrict__ b1, const float* __restrict__ Wa1,
                          const float* __restrict__ ba1, float* __restrict__ bz,
                          float* __restrict__ Xacc, float* __restrict__ accE) {
  const int b = blockIdx.x, t = threadIdx.x;
  #pragma unroll
  for (int i = 0; i < 4; ++i) Xacc[b * LDIM + i * DDIM + t] = 0.f;
  if (t == 0) accE[b] = 0.f;
  if (b == 0 && t < FDIM) {
    float a = ba1[t];
    for (int c = 0; c < DDIM; ++c) a += b1[c] * Wa1[c * FDIM + t];
    bz[t] = a;
  }
}

// ---- main: single pass over x. z-GEMM (32 cols) with x kept in registers;
// weighted per-segment x-sums accumulated into Xacc. M's big GEMM moved to
// finalize via linearity: M[s] = (Sum e_i x_i / E_s) @ W1 + b1.
// No LDS staging, no barriers in the K-loop. x read exactly once. ----
__global__ __launch_bounds__(256, 3) void fused_main(
    const float* __restrict__ x, const int* __restrict__ idxs,
    const unsigned short* __restrict__ w1tz, const float* __restrict__ bz,
    const float* __restrict__ Wa2, const float* __restrict__ ba2,
    float* __restrict__ Xacc, float* __restrict__ accE)
{
  __shared__ float zlds[BM][33];   // K-split z reduce (pad 33: conflict-free col reads)
  __shared__ float e_lds[BM];
  __shared__ int   seg_lds[BM];

  const int tid = threadIdx.x;
  const int lane = tid & 63;
  const int w = tid >> 6;          // wave owns k-range [w*256, w*256+256)
  const int g = lane >> 4;         // k-subchunk within a 32-k MFMA step
  const int cl = lane & 15;        // lane's row pair: {cl, 16+cl}
  const int row0 = blockIdx.x * BM;
  const int kw = w * 256;

  for (int i = tid; i < BM * 33; i += 256) ((float*)zlds)[i] = 0.f;
  if (tid < BM) seg_lds[tid] = idxs[row0 + tid];
  __syncthreads();

  const float* xa0 = x + (size_t)(row0 + cl) * LDIM + kw + g * 8;   // m=0 row
  const float* xa1 = xa0 + (size_t)16 * LDIM;                        // m=1 row
  const unsigned short* wz = w1tz + kw + (size_t)g * 8;

  f32x4 zacc[2][2];
  #pragma unroll
  for (int m = 0; m < 2; ++m)
    #pragma unroll
    for (int n = 0; n < 2; ++n) zacc[m][n] = (f32x4){0.f, 0.f, 0.f, 0.f};

  // retained x fragments: [ktl][m][kk], all indices static (rule #20)
  short8 xf[4][2][2];

  #pragma unroll
  for (int ktl = 0; ktl < 4; ++ktl) {
    #pragma unroll
    for (int kk = 0; kk < 2; ++kk) {
      {
        const float* p = xa0 + ktl * 64 + kk * 32;
        xf[ktl][0][kk] = pack8(*(const f32x4*)p, *(const f32x4*)(p + 4));
      }
      {
        const float* p = xa1 + ktl * 64 + kk * 32;
        xf[ktl][1][kk] = pack8(*(const f32x4*)p, *(const f32x4*)(p + 4));
      }
      #pragma unroll
      for (int n = 0; n < 2; ++n) {
        short8 bf = *(const short8*)(wz + (size_t)(n * 16 + cl) * LDIM + ktl * 64 + kk * 32);
        zacc[0][n] = __builtin_amdgcn_mfma_f32_16x16x32_bf16(xf[ktl][0][kk], bf, zacc[0][n], 0, 0, 0);
        zacc[1][n] = __builtin_amdgcn_mfma_f32_16x16x32_bf16(xf[ktl][1][kk], bf, zacc[1][n], 0, 0, 0);
      }
    }
    // bound staging liveness: don't let next ktl's loads hoist above (reg blow-up)
    __builtin_amdgcn_sched_barrier(0);
  }

  // K-split z partials -> LDS (f32 atomics), then logits by one wave
  #pragma unroll
  for (int m = 0; m < 2; ++m)
    #pragma unroll
    for (int n = 0; n < 2; ++n)
      #pragma unroll
      for (int q = 0; q < 4; ++q)
        atomicAdd(&zlds[m * 16 + g * 4 + q][n * 16 + cl], zacc[m][n][q]);
  __syncthreads();

  if (tid < BM) {
    const int r = tid;
    float lg = 0.f;
    #pragma unroll
    for (int c = 0; c < 32; ++c) {
      float e2 = exp2f((zlds[r][c] + bz[c]) * 2.8853900817779268f);   // e^{2z}
      lg += (1.f - 2.f / (e2 + 1.f)) * Wa2[c];                        // tanh(z)*Wa2
    }
    e_lds[r] = expf(lg + ba2[0]);   // logits bounded (|tanh|<=1) -> no max pass needed
  }
  __syncthreads();

  // ---- weighted per-k sums from the retained registers ----
  const float ea = e_lds[cl];
  const float eb = e_lds[16 + cl];
  const int   sa = seg_lds[cl];
  const int   sb = seg_lds[16 + cl];
  const int smin = seg_lds[0];
  const int smax = seg_lds[BM - 1];

  for (int s = smin; s <= smax; ++s) {   // runtime bounds OK: no reg-array runtime indexing
    const float wa = (sa == s) ? ea : 0.f;
    const float wb = (sb == s) ? eb : 0.f;
    float pt[4][2][8];
    #pragma unroll
    for (int ktl = 0; ktl < 4; ++ktl)
      #pragma unroll
      for (int kk = 0; kk < 2; ++kk) {
        union { short8 s8; u32x4 u; } ua, ub;
        ua.s8 = xf[ktl][0][kk];
        ub.s8 = xf[ktl][1][kk];
        #pragma unroll
        for (int p2 = 0; p2 < 4; ++p2) {
          pt[ktl][kk][p2 * 2]     = wa * bflo(ua.u[p2]) + wb * bflo(ub.u[p2]);
          pt[ktl][kk][p2 * 2 + 1] = wa * bfhi(ua.u[p2]) + wb * bfhi(ub.u[p2]);
        }
      }
    // fold across cl (lane bits 0-3): sums all 32 rows of the block
    #pragma unroll
    for (int mask = 1; mask <= 8; mask <<= 1)
      #pragma unroll
      for (int ktl = 0; ktl < 4; ++ktl)
        #pragma unroll
        for (int kk = 0; kk < 2; ++kk)
          #pragma unroll
          for (int j = 0; j < 8; ++j)
            pt[ktl][kk][j] += __shfl_xor(pt[ktl][kk][j], mask);
    if (cl == 0) {
      float* dst = Xacc + s * LDIM + kw + g * 8;
      #pragma unroll
      for (int ktl = 0; ktl < 4; ++ktl)
        #pragma unroll
        for (int kk = 0; kk < 2; ++kk)
          #pragma unroll
          for (int j = 0; j < 8; ++j)
            atomicAdd(dst + ktl * 64 + kk * 32 + j, pt[ktl][kk][j]);
    }
    if (w == 0) {
      float v = (lane < BM && seg_lds[lane & 31] == s) ? e_lds[lane & 31] : 0.f;
      v += __shfl_xor(v, 1); v += __shfl_xor(v, 2); v += __shfl_xor(v, 4);
      v += __shfl_xor(v, 8); v += __shfl_xor(v, 16);
      if (lane == 0) atomicAdd(&accE[s], v);
    }
  }
}

// ---- finalize: M[s] = (Xacc[s]/E)@W1 + b1 (f32 W1!); proj = normalize(M@Wp+bp) ----
__global__ void finalize_k(const float* __restrict__ Xacc, const float* __restrict__ accE,
                           const float* __restrict__ W1, const float* __restrict__ b1,
                           const float* __restrict__ Wp, const float* __restrict__ bp,
                           float* __restrict__ out) {
  __shared__ float Xn[LDIM];
  __shared__ float Ml[DDIM];
  const int s = blockIdx.x, t = threadIdx.x;
  const float E = accE[s];
  const float inv = (E > 0.f) ? 1.f / E : 0.f;
  #pragma unroll
  for (int i = 0; i < 4; ++i) Xn[i * DDIM + t] = Xacc[s * LDIM + i * DDIM + t] * inv;
  __syncthreads();
  float m = 0.f;
  for (int k = 0; k < LDIM; ++k) m += Xn[k] * W1[(size_t)k * DDIM + t];
  m = (E > 0.f) ? (m + b1[t]) : 0.f;   // empty segment -> M = 0 (matches reference)
  out[s * DDIM + t] = m;
  Ml[t] = m;
  __syncthreads();
  if (t < FDIM) {
    float p = bp[t];
    for (int c = 0; c < DDIM; ++c) p += Ml[c] * Wp[c * FDIM + t];
    float n2 = p * p;
    #pragma unroll
    for (int mask = 1; mask <= 16; mask <<= 1) n2 += __shfl_xor(n2, mask);
    out[NSEG * DDIM + s * FDIM + t] = p / fmaxf(sqrtf(n2), 1e-12f);
  }
}

extern "C" void kernel_launch(void* const* d_in, const int* in_sizes, int n_in,
                              void* d_out, int out_size, void* d_ws, size_t ws_size,
                              hipStream_t stream) {
  const float* x   = (const float*)d_in[0];
  const int*   idxs= (const int*)d_in[1];
  const float* W1  = (const float*)d_in[2];
  const float* b1  = (const float*)d_in[3];
  const float* Wa1 = (const float*)d_in[4];
  const float* ba1 = (const float*)d_in[5];
  const float* Wa2 = (const float*)d_in[6];
  const float* ba2 = (const float*)d_in[7];
  const float* Wp  = (const float*)d_in[8];
  const float* bp  = (const float*)d_in[9];
  float* out = (float*)d_out;

  char* ws = (char*)d_ws;
  unsigned short* w1tz = (unsigned short*)ws;         // 32*1024 bf16 = 65536 B
  float* bz   = (float*)(ws + 65536);                 // 32 f32
  float* Xacc = (float*)(ws + 65536 + 256);           // 64*1024 f32 = 262144 B
  float* accE = (float*)(ws + 65536 + 256 + 262144);  // 64 f32

  const int n = in_sizes[1];                          // 262144 rows
  prep_w1tz<<<LDIM, DDIM, 0, stream>>>(W1, Wa1, w1tz);
  prep_misc<<<NSEG, DDIM, 0, stream>>>(b1, Wa1, ba1, bz, Xacc, accE);
  fused_main<<<n / BM, 256, 0, stream>>>(x, idxs, w1tz, bz, Wa2, ba2, Xacc, accE);
  finalize_k<<<NSEG, DDIM, 0, stream>>>(Xacc, accE, W1, b1, Wp, bp, out);
}